// Round 16
// baseline (167.009 us; speedup 1.0000x reference)
//
#include <hip/hip_runtime.h>

// SIRD RK4, round 16: R13 stride-2 producer/consumer structure x depth-9 step.
// R9-R15 all pin at 116-124 cyc/tstep across six structures; R13 (stride-2
// LDS handoff, depth-12 step) was best at 116. This round runs R13's
// structure with the v-form depth-9 RK4 step (v = c*S - gm; each stage is
// 2 dependence levels: g_k = i_k*v_k, then i/v updates via fma). If the
// dependent-edge latency model (~10 cyc) holds, producer 2-tstep body
// ~175 cyc -> ~95 cyc/tstep. If this lands >=97 us kernel, the ~120
// cyc/step lone-wave floor is confirmed and the ceiling is declared.
//
// D from RK4-preserved invariant, v-form:
//   D = kD*(N - S - I), S = (v+gm)/c  =>  D = fma(-kD/c, v, fma(-kD, I, kDN2))
//   with kDN2 = kD*(N - gm/c).

#define N_POP 1.0e7f
#define T_PTS 2048
#define KSEG 32                  // LDS slots per segment
#define SEG_T (KSEG * 2)         // tsteps per segment (stride 2)
#define NSEG (T_PTS / SEG_T)     // 32 segments

// One RK4 step (h=1), 25 VALU slots, loop-carried depth 9. In-place on V,IV.
#define RK4_STEP(V, IV)                                                      \
    do {                                                                     \
        const float g1 = (V) * (IV);                           /* @1 */      \
        const float p1 = __builtin_fmaf(nch2gm, (IV), (V));    /* @1 */      \
        const float i2 = __builtin_fmaf(h2, g1, (IV));         /* @2 */      \
        const float v2 = __builtin_fmaf(nch2, g1, p1);         /* @2 */      \
        const float g2 = i2 * v2;                              /* @3 */      \
        const float p2 = __builtin_fmaf(nch2gm, i2, (V));      /* @3 */      \
        const float i3 = __builtin_fmaf(h2, g2, (IV));         /* @4 */      \
        const float v3 = __builtin_fmaf(nch2, g2, p2);         /* @4 */      \
        const float g3 = i3 * v3;                              /* @5 */      \
        const float p3 = __builtin_fmaf(nchgm, i3, (V));       /* @5 */      \
        const float i4 = (IV) + g3;                            /* @6 */      \
        const float v4 = __builtin_fmaf(nch, g3, p3);          /* @6 */      \
        const float g4 = i4 * v4;                              /* @7 */      \
        float bI = __builtin_fmaf(w, g1, (IV));                /* @2 */      \
        bI = __builtin_fmaf(w2, g2, bI);                       /* @4 */      \
        bI = __builtin_fmaf(w2, g3, bI);                       /* @6 */      \
        float a = __builtin_fmaf(nwc, g1, (V));                /* @2 */      \
        a = __builtin_fmaf(nwc2, g2, a);                       /* @4 */      \
        a = __builtin_fmaf(nwc2, g3, a);                       /* @6 */      \
        float si = __builtin_fmaf(2.0f, i2, (IV));             /* @3 */      \
        si = __builtin_fmaf(2.0f, i3, si);                     /* @5 */      \
        si = __builtin_fmaf(nwcgm, si, a);   /* a' @6: fold gm*si early */   \
        si = __builtin_fmaf(nwcgm, i4, si);                    /* @7 */      \
        (IV) = __builtin_fmaf(w, g4, bI);                      /* @8 */      \
        (V) = __builtin_fmaf(nwc, g4, si);                     /* @8 */      \
    } while (0)

__global__ __launch_bounds__(128, 1) void sird_kernel(const float* __restrict__ alpha,
                                                      float* __restrict__ out) {
    const int lane = threadIdx.x & 63;
    const int wave = threadIdx.x >> 6;        // 0 = producer, 1 = consumer
    const int s = blockIdx.x * 64 + lane;     // scenario (same for both waves)

    // SoA, double-buffered: [buf][var][slot][lane], var 0=v 1=I. 32 KiB.
    __shared__ float buf[2][2][KSEG][64];

    const float beta  = alpha[s * 3 + 0];
    const float gamma = alpha[s * 3 + 1];
    const float mu    = alpha[s * 3 + 2];

    const float c      = beta * (1.0f / N_POP);
    const float gm     = gamma + mu;
    const float h2     = 0.5f;                // h/2, h = 1
    const float nch2   = -0.5f * c;           // -c*h/2
    const float nch    = -c;                  // -c*h
    const float nch2gm = nch2 * gm;
    const float nchgm  = nch * gm;
    const float w      = 1.0f / 6.0f;
    const float w2     = 1.0f / 3.0f;         // 2w
    const float nwc    = -c * (1.0f / 6.0f);
    const float nwc2   = -c * (1.0f / 3.0f);  // 2*nwc
    const float nwcgm  = nwc * gm;
    const float kD     = mu / gm;             // gamma,mu > 0 a.s.
    const float nk     = -kD;
    const float nkc    = -kD / c;
    const float kDN2   = kD * ((float)N_POP - gm / c);

    float v = __builtin_fmaf(c, N_POP - 1.0f, -gm);   // v = c*S - gm
    float I = 1.0f;

    float2* __restrict__ orow = (float2*)out + (size_t)s * T_PTS;

    for (int seg = 0; seg <= NSEG; ++seg) {
        if (wave == 0) {
            if (seg < NSEG) {
                float* bv = &buf[seg & 1][0][0][lane];
                float* bI = &buf[seg & 1][1][0][lane];
#pragma unroll
                for (int k = 0; k < KSEG; ++k) {
                    bv[k * 64] = v;            // ds_write_b32, immediate offset
                    bI[k * 64] = I;
                    RK4_STEP(v, I);            // even -> odd
                    RK4_STEP(v, I);            // odd  -> next even
                }
            }
        } else {
            if (seg >= 1) {
                const float* qv = &buf[(seg - 1) & 1][0][0][lane];
                const float* qI = &buf[(seg - 1) & 1][1][0][lane];
                float2* op = orow + (size_t)(seg - 1) * SEG_T;
#pragma unroll
                for (int k = 0; k < KSEG; ++k) {
                    float vv = qv[k * 64];
                    float Iv = qI[k * 64];
                    const float D0 = __builtin_fmaf(nkc, vv,
                                     __builtin_fmaf(nk, Iv, kDN2));
                    op[2 * k] = make_float2(Iv, D0);
                    RK4_STEP(vv, Iv);          // bit-identical recompute of odd t
                    const float D1 = __builtin_fmaf(nkc, vv,
                                     __builtin_fmaf(nk, Iv, kDN2));
                    op[2 * k + 1] = make_float2(Iv, D1);
                }
            }
        }
        __syncthreads();
    }
}

extern "C" void kernel_launch(void* const* d_in, const int* in_sizes, int n_in,
                              void* d_out, int out_size, void* d_ws, size_t ws_size,
                              hipStream_t stream) {
    const float* alpha = (const float*)d_in[0];
    float* out = (float*)d_out;
    sird_kernel<<<dim3(T_PTS / 64), dim3(128), 0, stream>>>(alpha, out);
}